// Round 6
// baseline (73.137 us; speedup 1.0000x reference)
//
#include <hip/hip_runtime.h>

#define NSP   512
#define BATCH 1024

typedef __attribute__((ext_vector_type(8))) short bf16x8;
typedef __attribute__((ext_vector_type(4))) float f32x4;
typedef __attribute__((ext_vector_type(8))) unsigned short u16x8;

__device__ __forceinline__ unsigned short f2bf(float f) {
    union { float f; unsigned int u; } c; c.f = f;
    unsigned int u = c.u + (0x7FFFu + ((c.u >> 16) & 1u));  // RNE
    return (unsigned short)(u >> 16);
}

// Kernel 1 (prep): Mt[j][i] = bf16(J2[c(i,j)]) for i<j else 0, via coalesced
// 64x64 LDS tile transpose (J2 is row-contiguous in j for fixed i). Only the
// 36 upper tiles (ti<=tj) are ever read by ising_mfma (32*nch(jt) <= 64*(tj+1)).
// Also folds in: x -> bf16 convert, energy zero-init.
__global__ __launch_bounds__(256) void prep(const float* __restrict__ x,
                                            const float* __restrict__ J2,
                                            unsigned short* __restrict__ Mt,
                                            unsigned short* __restrict__ xb,
                                            float* __restrict__ energy) {
    __shared__ float tile[64][65];   // +1 pad: column reads conflict-free
    const int t  = threadIdx.x;
    const int ti = blockIdx.x >> 3;  // i-tile
    const int tj = blockIdx.x & 7;   // j-tile

    // duty 1: x -> bf16, spread over all 64 blocks (8 float4 per thread)
    {
        const float4* x4 = reinterpret_cast<const float4*>(x);
        int base = blockIdx.x * 256 + t;
        #pragma unroll
        for (int e = 0; e < 8; ++e) {
            float4 v = x4[base + 16384 * e];
            ushort4 o; o.x = f2bf(v.x); o.y = f2bf(v.y); o.z = f2bf(v.z); o.w = f2bf(v.w);
            reinterpret_cast<ushort4*>(xb)[base + 16384 * e] = o;
        }
    }
    // duty 2: zero energy (block 8 is a skipped lower tile -> free)
    if (blockIdx.x == 8) {
        float4 z = {0.0f, 0.0f, 0.0f, 0.0f};
        reinterpret_cast<float4*>(energy)[t] = z;   // 256 * 16B = 1024 floats
    }
    if (ti > tj) return;  // lower tiles never read

    const int i0 = ti * 64, j0 = tj * 64;
    // load (i,j) tile: lanes walk j -> J2 reads coalesced per i-row
    #pragma unroll
    for (int e = 0; e < 16; ++e) {
        int n = t + 256 * e;
        int r = n >> 6, cc = n & 63;
        int i = i0 + r, j = j0 + cc;
        float v = 0.0f;
        if (i < j) v = J2[i * (NSP - 1) - (i * (i - 1)) / 2 + (j - i - 1)];
        tile[r][cc] = v;
    }
    __syncthreads();
    // write Mt[j][i]: thread = (out-row jr, 16-wide i-span) -> 2x ushort8, coalesced
    {
        int jr = t >> 2;             // 0..63
        int s  = (t & 3) * 16;       // 0,16,32,48
        unsigned short o[16];
        #pragma unroll
        for (int e = 0; e < 16; ++e) o[e] = f2bf(tile[s + e][jr]);
        u16x8* dst = reinterpret_cast<u16x8*>(Mt + (size_t)(j0 + jr) * NSP + i0 + s);
        dst[0] = *reinterpret_cast<u16x8*>(o);
        dst[1] = *reinterpret_cast<u16x8*>(o + 8);
    }
}

// Kernel 2: one wave per 16(b) x 16(j) tile, mfma_f32_16x16x32_bf16 over the
// triangularly-truncated k-range; fused x*(C+J1) weighting; 16-lane shuffle
// reduce + 4-wave LDS block reduce -> 16 atomics per block.
__global__ __launch_bounds__(256) void ising_mfma(const float* __restrict__ x,
                                                  const float* __restrict__ J1,
                                                  const unsigned short* __restrict__ Mt,
                                                  const unsigned short* __restrict__ xb,
                                                  float* __restrict__ energy) {
    __shared__ float red[4][16];
    const int tid  = threadIdx.x;
    const int w    = tid >> 6;           // wave 0..3
    const int lane = tid & 63;
    const int bt   = blockIdx.x;         // b-tile 0..63
    const int jt   = blockIdx.y * 4 + w; // j-tile 0..31 (one per wave)
    const int b0   = bt * 16;
    const int j0   = jt * 16;
    const int r16  = lane & 15;
    const int kg   = lane >> 4;

    const int nch = (16 * jt + 46) >> 5;     // k-chunks covering i <= j0+14

    const unsigned short* Ap = xb + (size_t)(b0 + r16) * NSP + kg * 8;
    const unsigned short* Bp = Mt + (size_t)(j0 + r16) * NSP + kg * 8;

    f32x4 acc = {0.0f, 0.0f, 0.0f, 0.0f};
    #pragma unroll 4
    for (int ch = 0; ch < nch; ++ch) {
        bf16x8 a = *reinterpret_cast<const bf16x8*>(Ap + ch * 32);
        bf16x8 b = *reinterpret_cast<const bf16x8*>(Bp + ch * 32);
        acc = __builtin_amdgcn_mfma_f32_16x16x32_bf16(a, b, acc, 0, 0, 0);
    }

    // epilogue: energy[b0+row] += x[b0+row, j] * (acc + J1[j]) summed over 16 j
    const int jcol = j0 + r16;
    const float j1 = J1[jcol];
    float part[4];
    #pragma unroll
    for (int r = 0; r < 4; ++r) {
        float xw = x[(size_t)(b0 + kg * 4 + r) * NSP + jcol];
        part[r] = xw * (acc[r] + j1);
    }
    #pragma unroll
    for (int off = 8; off >= 1; off >>= 1)
        #pragma unroll
        for (int r = 0; r < 4; ++r)
            part[r] += __shfl_xor(part[r], off, 64);

    if (r16 == 0) {   // lanes 0,16,32,48 hold rows kg*4+r
        #pragma unroll
        for (int r = 0; r < 4; ++r) red[w][kg * 4 + r] = part[r];
    }
    __syncthreads();
    if (tid < 16) {
        float s = red[0][tid] + red[1][tid] + red[2][tid] + red[3][tid];
        atomicAdd(&energy[b0 + tid], s);
    }
}

extern "C" void kernel_launch(void* const* d_in, const int* in_sizes, int n_in,
                              void* d_out, int out_size, void* d_ws, size_t ws_size,
                              hipStream_t stream) {
    const float* x  = (const float*)d_in[0];  // [1024, 512]
    const float* J1 = (const float*)d_in[1];  // [512]
    const float* J2 = (const float*)d_in[2];  // [130816]
    // d_in[3] = pairs, unused (closed-form index)
    unsigned short* Mt = (unsigned short*)d_ws;                    // 512 KB
    unsigned short* xb = (unsigned short*)((char*)d_ws + 524288);  // 1 MB
    float* energy = (float*)d_out;                                 // [1024]

    prep<<<dim3(64), 256, 0, stream>>>(x, J2, Mt, xb, energy);
    ising_mfma<<<dim3(BATCH / 16, 8), 256, 0, stream>>>(x, J1, Mt, xb, energy);
}

// Round 10
// 68.870 us; speedup vs baseline: 1.0620x; 1.0620x over previous
//
#include <hip/hip_runtime.h>

#define NSP   512
#define BATCH 1024

typedef __attribute__((ext_vector_type(8))) short bf16x8;
typedef __attribute__((ext_vector_type(4))) float f32x4;

__device__ __forceinline__ unsigned short f2bf(float f) {
    union { float f; unsigned int u; } c; c.f = f;
    unsigned int u = c.u + (0x7FFFu + ((c.u >> 16) & 1u));  // RNE
    return (unsigned short)(u >> 16);
}

// Kernel 1 (prep, round-5 proven form): Mt[j][i] = bf16(J2[c(i,j)]) for i<j
// else 0 (c = triu lex index, contiguous in j for fixed i). J2 is 523 KB ->
// L2-resident, so the strided gather is latency-hidden by 16 waves/CU of TLP
// (the 64-block coalesced-transpose variant was 5 us SLOWER - round 6).
// Folds in: x -> bf16 convert, energy zero-init.
__global__ __launch_bounds__(256) void prep(const float* __restrict__ x,
                                            const float* __restrict__ J2,
                                            unsigned short* __restrict__ Mt,
                                            unsigned short* __restrict__ xb,
                                            float* __restrict__ energy) {
    int idx = blockIdx.x * 256 + threadIdx.x;   // 1024 blocks -> 262144 threads
    int j = idx >> 9;
    int i = idx & (NSP - 1);
    float v = 0.0f;
    if (i < j) v = J2[i * (NSP - 1) - (i * (i - 1)) / 2 + (j - i - 1)];
    Mt[idx] = f2bf(v);                          // coalesced in i
    if (idx < (BATCH * NSP) / 4) {              // first 131072 threads: x -> bf16
        float4 xv = reinterpret_cast<const float4*>(x)[idx];
        ushort4 o;
        o.x = f2bf(xv.x); o.y = f2bf(xv.y); o.z = f2bf(xv.z); o.w = f2bf(xv.w);
        reinterpret_cast<ushort4*>(xb)[idx] = o;
    }
    if (idx < BATCH) energy[idx] = 0.0f;
}

// Kernel 2: one wave per 16(b) x 16(j) tile, mfma_f32_16x16x32_bf16 over the
// triangularly-truncated k-range; fused x*(C+J1) weighting; 16-lane shuffle
// reduce + 4-wave LDS block reduce -> 16 atomics per block (8-way contention).
__global__ __launch_bounds__(256) void ising_mfma(const float* __restrict__ x,
                                                  const float* __restrict__ J1,
                                                  const unsigned short* __restrict__ Mt,
                                                  const unsigned short* __restrict__ xb,
                                                  float* __restrict__ energy) {
    __shared__ float red[4][16];
    const int tid  = threadIdx.x;
    const int w    = tid >> 6;           // wave 0..3
    const int lane = tid & 63;
    const int bt   = blockIdx.x;         // b-tile 0..63
    const int jt   = blockIdx.y * 4 + w; // j-tile 0..31 (one per wave)
    const int b0   = bt * 16;
    const int j0   = jt * 16;
    const int r16  = lane & 15;
    const int kg   = lane >> 4;

    const int nch = (16 * jt + 46) >> 5;     // k-chunks covering i <= j0+14

    const unsigned short* Ap = xb + (size_t)(b0 + r16) * NSP + kg * 8;
    const unsigned short* Bp = Mt + (size_t)(j0 + r16) * NSP + kg * 8;

    f32x4 acc = {0.0f, 0.0f, 0.0f, 0.0f};
    #pragma unroll 4
    for (int ch = 0; ch < nch; ++ch) {
        bf16x8 a = *reinterpret_cast<const bf16x8*>(Ap + ch * 32);
        bf16x8 b = *reinterpret_cast<const bf16x8*>(Bp + ch * 32);
        acc = __builtin_amdgcn_mfma_f32_16x16x32_bf16(a, b, acc, 0, 0, 0);
    }

    // epilogue: energy[b0+row] += x[b0+row, j] * (acc + J1[j]) summed over 16 j
    const int jcol = j0 + r16;
    const float j1 = J1[jcol];
    float part[4];
    #pragma unroll
    for (int r = 0; r < 4; ++r) {
        float xw = x[(size_t)(b0 + kg * 4 + r) * NSP + jcol];
        part[r] = xw * (acc[r] + j1);
    }
    #pragma unroll
    for (int off = 8; off >= 1; off >>= 1)
        #pragma unroll
        for (int r = 0; r < 4; ++r)
            part[r] += __shfl_xor(part[r], off, 64);

    if (r16 == 0) {   // lanes 0,16,32,48 hold rows kg*4+r
        #pragma unroll
        for (int r = 0; r < 4; ++r) red[w][kg * 4 + r] = part[r];
    }
    __syncthreads();
    if (tid < 16) {
        float s = red[0][tid] + red[1][tid] + red[2][tid] + red[3][tid];
        atomicAdd(&energy[b0 + tid], s);
    }
}

extern "C" void kernel_launch(void* const* d_in, const int* in_sizes, int n_in,
                              void* d_out, int out_size, void* d_ws, size_t ws_size,
                              hipStream_t stream) {
    const float* x  = (const float*)d_in[0];  // [1024, 512]
    const float* J1 = (const float*)d_in[1];  // [512]
    const float* J2 = (const float*)d_in[2];  // [130816]
    // d_in[3] = pairs, unused (closed-form index)
    unsigned short* Mt = (unsigned short*)d_ws;                    // 512 KB
    unsigned short* xb = (unsigned short*)((char*)d_ws + 524288);  // 1 MB
    float* energy = (float*)d_out;                                 // [1024]

    prep<<<dim3((NSP * NSP) / 256), 256, 0, stream>>>(x, J2, Mt, xb, energy);
    ising_mfma<<<dim3(BATCH / 16, 8), 256, 0, stream>>>(x, J1, Mt, xb, energy);
}